// Round 13
// baseline (429.004 us; speedup 1.0000x reference)
//
#include <hip/hip_runtime.h>
#include <hip/hip_fp16.h>

// ---------------------------------------------------------------------------
// GCN 3-layer forward:  (GCNConv -> BN) x2 -> GCNConv
// N=100000, E=1600000, IN=H=128, OUT=64
// Round 12: degree-sorted node permutation (per-bucket bitonic in
//           bucket_sort_k) -> near-uniform edge-loop trip counts per wave
//           (kills Poisson-degree divergence). Gather/GEMM else unchanged.
// ---------------------------------------------------------------------------

constexpr int BSH = 7;            // 128 nodes per bucket
constexpr int NXCD = 8;

typedef _Float16 half8 __attribute__((ext_vector_type(8)));
typedef float f32x4 __attribute__((ext_vector_type(4)));

static __device__ inline ushort f2h(float f) {
    union { __half h; ushort u; } cv;
    cv.h = __float2half_rn(f);
    return cv.u;
}
static __device__ inline float2 h2f2(unsigned int u) {
    union { unsigned int u; __half2 h; } cv;
    cv.u = u;
    return __half22float2(cv.h);
}
static __device__ inline __half2 u2h2(unsigned int u) {
    union { unsigned int u; __half2 h; } cv;
    cv.u = u;
    return cv.h;
}

// packed-f16 accumulate: one uint4 (8 f16) into 4 half2 accumulators
#define ACCPK(v) do { \
    acch[0] = __hadd2(acch[0], u2h2((v).x)); \
    acch[1] = __hadd2(acch[1], u2h2((v).y)); \
    acch[2] = __hadd2(acch[2], u2h2((v).z)); \
    acch[3] = __hadd2(acch[3], u2h2((v).w)); \
} while (0)

// ---- phase A: per-xcd bucket histogram + W^T f16 prep (blocks 0-2) --------
__global__ __launch_bounds__(256) void countwt_k(const int* __restrict__ dst,
                                                 int* __restrict__ hist,
                                                 int E, int EPB, int nbuk,
                                                 const float* __restrict__ W1,
                                                 const float* __restrict__ W2,
                                                 const float* __restrict__ W3,
                                                 ushort* __restrict__ wt1,
                                                 ushort* __restrict__ wt2,
                                                 ushort* __restrict__ wt3) {
    if (blockIdx.x < 3) {
        const float* W; ushort* WT; int OUTD;
        if (blockIdx.x == 0)      { W = W1; WT = wt1; OUTD = 128; }
        else if (blockIdx.x == 1) { W = W2; WT = wt2; OUTD = 128; }
        else                      { W = W3; WT = wt3; OUTD = 64; }
        const int tot = 128 * OUTD;
        for (int idx = threadIdx.x; idx < tot; idx += 256) {
            int nq = idx >> 7;          // output col
            int k  = idx & 127;         // input k
            WT[idx] = f2h(W[k * OUTD + nq]);
        }
        return;
    }
    const int bid = blockIdx.x - 3;
    __shared__ int lh[1024];
    for (int i = threadIdx.x; i < nbuk; i += 256) lh[i] = 0;
    __syncthreads();
    const int e0 = bid * EPB;
    const int e1 = min(e0 + EPB, E);
    for (int e = e0 + threadIdx.x; e < e1; e += 256)
        atomicAdd(&lh[dst[e] >> BSH], 1);
    __syncthreads();
    const int xcd = bid & (NXCD - 1);
    for (int i = threadIdx.x; i < nbuk; i += 256) {
        int v = lh[i];
        if (v) atomicAdd(&hist[xcd * nbuk + i], v);
    }
}

// ---- phase B: scan hist; zero BOTH BN stats banks (stats[0..511]) ---------
__global__ __launch_bounds__(256) void scan_hist_k(const int* __restrict__ hist,
                                                   int* __restrict__ cur,
                                                   int* __restrict__ bstart,
                                                   int* __restrict__ row_ptr,
                                                   float* __restrict__ stats,
                                                   int nbuk, int n, int E) {
    stats[threadIdx.x] = 0.f;
    stats[threadIdx.x + 256] = 0.f;
    const int NT = nbuk * NXCD;          // <= 8192 assumed
    const int C = (NT + 255) / 256;      // <= 32
    int vals[32];
    const int tid = threadIdx.x;
    int sum = 0;
#pragma unroll
    for (int k = 0; k < 32; ++k) {
        if (k >= C) break;
        int key = tid * C + k;
        int v = 0;
        if (key < NT) {
            int b = key >> 3, x = key & 7;
            v = hist[x * nbuk + b];
        }
        vals[k] = v;
        sum += v;
    }
    __shared__ int part[256];
    part[tid] = sum;
    __syncthreads();
    for (int off = 1; off < 256; off <<= 1) {
        int t = 0;
        if (tid >= off) t = part[tid - off];
        __syncthreads();
        part[tid] += t;
        __syncthreads();
    }
    int run = (tid == 0) ? 0 : part[tid - 1];
#pragma unroll
    for (int k = 0; k < 32; ++k) {
        if (k >= C) break;
        int key = tid * C + k;
        if (key < NT) {
            int b = key >> 3, x = key & 7;
            cur[x * nbuk + b] = run;
            if (x == 0) bstart[b] = run;
        }
        run += vals[k];
    }
    if (tid == 0) { bstart[nbuk] = E; row_ptr[n] = E; }
}

// ---- phase C: two-pass LDS-aggregated scatter into (bucket, xcd) segments -
__global__ __launch_bounds__(256) void scatter_bucket_k(const int* __restrict__ src,
                                                        const int* __restrict__ dst,
                                                        int* __restrict__ cur,
                                                        unsigned int* __restrict__ ebuf,
                                                        int E, int EPB, int nbuk) {
    __shared__ int lh[1024];
    __shared__ int base[1024];
    for (int i = threadIdx.x; i < nbuk; i += 256) lh[i] = 0;
    __syncthreads();
    const int e0 = blockIdx.x * EPB;
    const int e1 = min(e0 + EPB, E);
    const int xcd = blockIdx.x & (NXCD - 1);
    for (int e = e0 + threadIdx.x; e < e1; e += 256)
        atomicAdd(&lh[dst[e] >> BSH], 1);
    __syncthreads();
    for (int i = threadIdx.x; i < nbuk; i += 256) {
        int v = lh[i];
        base[i] = v ? atomicAdd(&cur[xcd * nbuk + i], v) : 0;
        lh[i] = 0;                      // becomes cursor
    }
    __syncthreads();
    for (int e = e0 + threadIdx.x; e < e1; e += 256) {
        int d = dst[e];
        int s = src[e];
        int b = d >> BSH;
        int pos = base[b] + atomicAdd(&lh[b], 1);
        ebuf[pos] = ((unsigned int)s << BSH) | (unsigned int)(d & 127);
    }
}

// ---- phase D: counting sort -> esrc + row_ptr + dis + degree-sorted perm --
__global__ __launch_bounds__(256) void bucket_sort_k(const unsigned int* __restrict__ ebuf,
                                                     const int* __restrict__ bstart,
                                                     int* __restrict__ row_ptr,
                                                     int* __restrict__ esrc,
                                                     float* __restrict__ dis,
                                                     int* __restrict__ perm, int n) {
    const int b = blockIdx.x;
    const int beg = bstart[b];
    const int end = bstart[b + 1];
    __shared__ int cnt[128], off[128];
    __shared__ unsigned int dkey[128];
    if (threadIdx.x < 128) cnt[threadIdx.x] = 0;
    __syncthreads();
    for (int i = beg + threadIdx.x; i < end; i += 256)
        atomicAdd(&cnt[ebuf[i] & 127], 1);
    __syncthreads();
    if (threadIdx.x < 128) off[threadIdx.x] = cnt[threadIdx.x];
    __syncthreads();
    for (int d = 1; d < 128; d <<= 1) {
        int t = 0;
        if (threadIdx.x < 128 && threadIdx.x >= d) t = off[threadIdx.x - d];
        __syncthreads();
        if (threadIdx.x < 128) off[threadIdx.x] += t;
        __syncthreads();
    }
    if (threadIdx.x < 128) {
        int deg = cnt[threadIdx.x];
        int ex = off[threadIdx.x] - deg;                // exclusive
        int node = (b << BSH) + threadIdx.x;
        unsigned int dv = 0xFFFFFFu;                    // n-overflow sorts last
        if (node < n) {
            row_ptr[node] = beg + ex;
            dis[node] = rsqrtf((float)deg + 1.0f);      // +1 self loop
            dv = (unsigned int)deg;
        }
        dkey[threadIdx.x] = (dv << 7) | (unsigned int)threadIdx.x;
        cnt[threadIdx.x] = ex;                          // reuse as cursor
    }
    __syncthreads();
    for (int i = beg + threadIdx.x; i < end; i += 256) {
        unsigned int p = ebuf[i];
        int l = (int)(p & 127);
        int pos = beg + atomicAdd(&cnt[l], 1);
        esrc[pos] = (int)(p >> BSH);
    }
    // bitonic sort the 128 (deg, idx) keys ascending -> degree-sorted perm
    for (int k = 2; k <= 128; k <<= 1) {
        for (int j = k >> 1; j > 0; j >>= 1) {
            __syncthreads();
            if (threadIdx.x < 64) {
                int i = threadIdx.x;
                int xi = ((i & ~(j - 1)) << 1) | (i & (j - 1));
                int yi = xi | j;
                unsigned int a = dkey[xi], c = dkey[yi];
                bool asc = (xi & k) == 0;
                if ((a > c) == asc) { dkey[xi] = c; dkey[yi] = a; }
            }
        }
    }
    __syncthreads();
    if (threadIdx.x < 128)
        perm[(b << BSH) + threadIdx.x] = (b << BSH) + (int)(dkey[threadIdx.x] & 127u);
}

// ------- register MFMA GEMM: Hs = f16( (BN(X) @ W) * dis ) -----------------
// Zero-LDS main path. Block = 4 waves x 16 rows = 64 rows. A from global X
// (f32 or f16); B from f16 W^T (L1-resident). When BNIN, each block computes
// BN scale/shift from the raw stats bank (sums|sumsq) + (g,be) into LDS.
// Hs layout: [NCHUNK][N][32 f16], chunk c holds columns [32c, 32c+32).
template <int OUTD, bool XF16, bool BNIN>
__global__ __launch_bounds__(256) void gemm_reg_k(const void* __restrict__ Xv,
                                                  const ushort* __restrict__ WT,
                                                  const float* __restrict__ sums,
                                                  const float* __restrict__ gg,
                                                  const float* __restrict__ be,
                                                  const float* __restrict__ dis,
                                                  ushort* __restrict__ Hs, int nn) {
    constexpr int NCT = OUTD / 16;       // col tiles: 8 or 4
    __shared__ __align__(16) float s_scale[BNIN ? 128 : 4];
    __shared__ __align__(16) float s_shift[BNIN ? 128 : 4];
    if (BNIN) {
        if (threadIdx.x < 128) {
            int c = threadIdx.x;
            float inv_n = 1.0f / (float)nn;
            float m = sums[c] * inv_n;
            float v = sums[c + 128] * inv_n - m * m;
            float sc = rsqrtf(v + 1e-5f) * gg[c];
            s_scale[c] = sc;
            s_shift[c] = be[c] - m * sc;
        }
        __syncthreads();
    }

    const int wave = threadIdx.x >> 6;
    const int lane = threadIdx.x & 63;
    const int l15 = lane & 15;
    const int kg = lane >> 4;            // 0..3
    const int row = blockIdx.x * 64 + wave * 16 + l15;

    // A fragments: row fixed, k = kk*32 + kg*8 + [0..8)
    half8 a[4];
#pragma unroll
    for (int kk = 0; kk < 4; ++kk) {
        float v[8];
        if (row < nn) {
            if (XF16) {
                const uint4* xp = (const uint4*)((const ushort*)Xv + (size_t)row * 128
                                                 + kk * 32 + kg * 8);
                uint4 raw = *xp;
                float2 f;
                f = h2f2(raw.x); v[0] = f.x; v[1] = f.y;
                f = h2f2(raw.y); v[2] = f.x; v[3] = f.y;
                f = h2f2(raw.z); v[4] = f.x; v[5] = f.y;
                f = h2f2(raw.w); v[6] = f.x; v[7] = f.y;
            } else {
                const float4* xp = (const float4*)((const float*)Xv + (size_t)row * 128
                                                   + kk * 32 + kg * 8);
                float4 v0 = xp[0];
                float4 v1 = xp[1];
                v[0] = v0.x; v[1] = v0.y; v[2] = v0.z; v[3] = v0.w;
                v[4] = v1.x; v[5] = v1.y; v[6] = v1.z; v[7] = v1.w;
            }
            if (BNIN) {
                int kq = kk * 8 + kg * 2;
                float4 s0 = ((const float4*)s_scale)[kq];
                float4 s1 = ((const float4*)s_scale)[kq + 1];
                float4 h0 = ((const float4*)s_shift)[kq];
                float4 h1 = ((const float4*)s_shift)[kq + 1];
                v[0] = v[0] * s0.x + h0.x;
                v[1] = v[1] * s0.y + h0.y;
                v[2] = v[2] * s0.z + h0.z;
                v[3] = v[3] * s0.w + h0.w;
                v[4] = v[4] * s1.x + h1.x;
                v[5] = v[5] * s1.y + h1.y;
                v[6] = v[6] * s1.z + h1.z;
                v[7] = v[7] * s1.w + h1.w;
            }
#pragma unroll
            for (int j = 0; j < 8; ++j) a[kk][j] = (_Float16)v[j];
        } else {
#pragma unroll
            for (int j = 0; j < 8; ++j) a[kk][j] = (_Float16)0.f;
        }
    }

    f32x4 acc[NCT];
#pragma unroll
    for (int ct = 0; ct < NCT; ++ct) acc[ct] = (f32x4){0.f, 0.f, 0.f, 0.f};

#pragma unroll
    for (int kk = 0; kk < 4; ++kk) {
#pragma unroll
        for (int ct = 0; ct < NCT; ++ct) {
            half8 bfr = *(const half8*)&WT[(ct * 16 + l15) * 128 + kk * 32 + kg * 8];
            acc[ct] = __builtin_amdgcn_mfma_f32_16x16x32_f16(a[kk], bfr, acc[ct], 0, 0, 0);
        }
    }

    // D: col = lane&15 (within ct), row = kg*4 + reg (within wave tile)
    const int mbase = blockIdx.x * 64 + wave * 16 + kg * 4;
    float dm[4];
#pragma unroll
    for (int reg = 0; reg < 4; ++reg) {
        int m = mbase + reg;
        dm[reg] = (m < nn) ? dis[m] : 0.f;
    }
#pragma unroll
    for (int ct = 0; ct < NCT; ++ct) {
        int ncol = ct * 16 + l15;
        size_t cb = (size_t)(ncol >> 5) * nn * 32 + (ncol & 31);
#pragma unroll
        for (int reg = 0; reg < 4; ++reg) {
            int m = mbase + reg;
            if (m < nn) Hs[cb + (size_t)m * 32] = f2h(acc[ct][reg] * dm[reg]);
        }
    }
}

// ---------------- chunked gather aggregation (+ fused BN stats) ------------
// Per chunk c (32 cols): O[i][32c..32c+32) = dis[i]*(Hs_c[i] + sum Hs_c[src]) + b
// 4 lanes per 64B row; unroll-8; packed-f16 accumulation; nodes processed in
// degree-sorted perm order -> uniform trip counts within a wave.
template <int OUTD, bool STATS, bool OUTF16>
__global__ __launch_bounds__(256) void gather_k(const ushort* __restrict__ Hs,
                                                const float* __restrict__ dis,
                                                const float* __restrict__ b,
                                                const int* __restrict__ row_ptr,
                                                const int* __restrict__ esrc,
                                                const int* __restrict__ perm,
                                                void* __restrict__ Ov,
                                                float* __restrict__ sums,
                                                float* __restrict__ sumsq, int n) {
    constexpr int NCHUNK = OUTD / 32;   // 4 or 2

    __shared__ float s_sum[32];
    __shared__ float s_sq[32];
    if (STATS) {
        if (threadIdx.x < 32) { s_sum[threadIdx.x] = 0.f; s_sq[threadIdx.x] = 0.f; }
        __syncthreads();
    }

    const int chunk = blockIdx.x & (NCHUNK - 1);
    const int nblk  = blockIdx.x / NCHUNK;
    const int g     = threadIdx.x >> 2;     // slot within block: 0..63
    const int lane  = threadIdx.x & 3;      // uint4 within the 64B row
    const int node  = perm[nblk * 64 + g];  // degree-sorted node id

    __half2 acch[4];
#pragma unroll
    for (int c = 0; c < 4; ++c) acch[c] = __half2(__float2half_rn(0.f), __float2half_rn(0.f));
    float o[8];
#pragma unroll
    for (int c = 0; c < 8; ++c) o[c] = 0.f;

    if (node < n) {
        const uint4* Hc = (const uint4*)Hs + (size_t)chunk * n * 4;  // 4 uint4/node

        {   // self row (dis pre-folded into Hs)
            uint4 v = Hc[(size_t)node * 4 + lane];
            ACCPK(v);
        }
        const int beg = row_ptr[node];
        const int end = row_ptr[node + 1];
        int j = beg;
        const int end8 = beg + ((end - beg) & ~7);
        for (; j < end8; j += 8) {
            int s[8];
#pragma unroll
            for (int u = 0; u < 8; ++u) s[u] = esrc[j + u];
            uint4 va[8];
#pragma unroll
            for (int u = 0; u < 8; ++u) va[u] = Hc[(size_t)s[u] * 4 + lane];
#pragma unroll
            for (int u = 0; u < 8; ++u) { ACCPK(va[u]); }
        }
        for (; j < end; ++j) {
            int s = esrc[j];
            uint4 a = Hc[(size_t)s * 4 + lane];
            ACCPK(a);
        }

        float dd = dis[node];
        const float4* B4 = (const float4*)b + chunk * 8 + lane * 2;
        float4 b0 = B4[0];
        float4 b1 = B4[1];
        float2 f0 = __half22float2(acch[0]);
        float2 f1 = __half22float2(acch[1]);
        float2 f2 = __half22float2(acch[2]);
        float2 f3 = __half22float2(acch[3]);
        o[0] = f0.x * dd + b0.x;
        o[1] = f0.y * dd + b0.y;
        o[2] = f1.x * dd + b0.z;
        o[3] = f1.y * dd + b0.w;
        o[4] = f2.x * dd + b1.x;
        o[5] = f2.y * dd + b1.y;
        o[6] = f3.x * dd + b1.z;
        o[7] = f3.y * dd + b1.w;

        if (OUTF16) {
            union { ushort us[8]; uint4 v; } pk;
#pragma unroll
            for (int c = 0; c < 8; ++c) pk.us[c] = f2h(o[c]);
            ((uint4*)Ov)[(size_t)node * (OUTD / 8) + chunk * 4 + lane] = pk.v;
        } else {
            float4* O4 = (float4*)Ov + (size_t)node * (OUTD / 4) + chunk * 8 + lane * 2;
            O4[0] = make_float4(o[0], o[1], o[2], o[3]);
            O4[1] = make_float4(o[4], o[5], o[6], o[7]);
        }
    }

    if (STATS) {
        // 16 lanes of a wave with equal (lane&3) hold the same 8 columns
        float sv[8], qv[8];
#pragma unroll
        for (int c = 0; c < 8; ++c) { sv[c] = o[c]; qv[c] = o[c] * o[c]; }
#pragma unroll
        for (int c = 0; c < 8; ++c) {
#pragma unroll
            for (int m = 4; m <= 32; m <<= 1) {
                sv[c] += __shfl_xor(sv[c], m);
                qv[c] += __shfl_xor(qv[c], m);
            }
        }
        if ((threadIdx.x & 63) < 4) {
            int c0 = lane * 8;
#pragma unroll
            for (int c = 0; c < 8; ++c) {
                atomicAdd(&s_sum[c0 + c], sv[c]);
                atomicAdd(&s_sq[c0 + c], qv[c]);
            }
        }
        __syncthreads();
        if (threadIdx.x < 32) {
            atomicAdd(&sums[chunk * 32 + threadIdx.x], s_sum[threadIdx.x]);
            atomicAdd(&sumsq[chunk * 32 + threadIdx.x], s_sq[threadIdx.x]);
        }
    }
}

// ---------------------------------------------------------------------------
extern "C" void kernel_launch(void* const* d_in, const int* in_sizes, int n_in,
                              void* d_out, int out_size, void* d_ws, size_t ws_size,
                              hipStream_t stream) {
    const float* x   = (const float*)d_in[0];
    const int*   ei  = (const int*)d_in[1];
    const float* W1  = (const float*)d_in[2];
    const float* b1  = (const float*)d_in[3];
    const float* g1  = (const float*)d_in[4];
    const float* be1 = (const float*)d_in[5];
    const float* W2  = (const float*)d_in[6];
    const float* b2  = (const float*)d_in[7];
    const float* g2  = (const float*)d_in[8];
    const float* be2 = (const float*)d_in[9];
    const float* W3  = (const float*)d_in[10];
    const float* b3  = (const float*)d_in[11];
    float* out = (float*)d_out;

    const int N = in_sizes[0] / 128;
    const int E = in_sizes[1] / 2;
    const int* src = ei;
    const int* dst = ei + E;
    const int NBUK = (N + 127) >> BSH;

    // ---- workspace layout ----
    float* wsp   = (float*)d_ws;
    float* dis   = wsp;                               // N f32
    float* stats = wsp + N;                           // 512 f32 (2 banks)
    ushort* wt1  = (ushort*)(stats + 512);            // 128*128 f16
    ushort* wt2  = wt1 + 128 * 128;
    ushort* wt3  = wt2 + 128 * 128;                   // 128*64 f16
    int*   hist   = (int*)(wt3 + 128 * 64);           // NBUK*8
    int*   cur    = hist + NBUK * NXCD;               // NBUK*8
    int*   bstart = cur + NBUK * NXCD;                // NBUK+1
    int*   row_ptr = bstart + NBUK + 1 + 63;          // N+1
    float* bufA  = (float*)((((uintptr_t)(row_ptr + N + 1)) + 255) & ~(uintptr_t)255);
    float* bufB  = bufA + (size_t)N * 128;            // N*128 region (f16 used)
    unsigned int* ebuf = (unsigned int*)(bufB + (size_t)N * 128);  // E u32
    int*   esrc  = (int*)(ebuf + E);                  // E int
    int*   perm  = esrc + E;                          // NBUK*128 int

    ushort* Hs  = (ushort*)bufA;                      // [NCHUNK][N][32] f16
    ushort* Bf16 = (ushort*)bufB;                     // [N][128] f16 inter-layer

    float* statsA = stats;        // sums|sumsq layer 1
    float* statsB = stats + 256;  // sums|sumsq layer 2

    const int BS = 256;
    dim3 blk(BS);
    const int SGRID = 128;                 // count/scatter blocks (multiple of 8)
    const int EPB = (E + SGRID - 1) / SGRID;

    // ---- bucket-sorted CSR build ----
    hipMemsetAsync(hist, 0, (size_t)NBUK * NXCD * 4, stream);
    countwt_k<<<dim3(SGRID + 3), blk, 0, stream>>>(dst, hist, E, EPB, NBUK,
                                                   W1, W2, W3, wt1, wt2, wt3);
    scan_hist_k<<<dim3(1), blk, 0, stream>>>(hist, cur, bstart, row_ptr, stats, NBUK, N, E);
    scatter_bucket_k<<<dim3(SGRID), blk, 0, stream>>>(src, dst, cur, ebuf, E, EPB, NBUK);
    bucket_sort_k<<<dim3(NBUK), blk, 0, stream>>>(ebuf, bstart, row_ptr, esrc, dis, perm, N);

    const int gemm_grid = (N + 63) / 64;
    const int NBg = (N + 63) / 64;      // gather node-blocks (64 nodes/block)

    // ---- layer 1 ----
    gemm_reg_k<128, false, false><<<dim3(gemm_grid), blk, 0, stream>>>(
        x, wt1, nullptr, nullptr, nullptr, dis, Hs, N);
    gather_k<128, true, true><<<dim3(NBg * 4), blk, 0, stream>>>(
        Hs, dis, b1, row_ptr, esrc, perm, Bf16, statsA, statsA + 128, N);

    // ---- layer 2 (BN computed per-block from statsA inside GEMM) ----
    gemm_reg_k<128, true, true><<<dim3(gemm_grid), blk, 0, stream>>>(
        Bf16, wt2, statsA, g1, be1, dis, Hs, N);
    gather_k<128, true, true><<<dim3(NBg * 4), blk, 0, stream>>>(
        Hs, dis, b2, row_ptr, esrc, perm, Bf16, statsB, statsB + 128, N);

    // ---- layer 3 (OUT = 64, BN from statsB, f32 straight to d_out) ----
    gemm_reg_k<64, true, true><<<dim3(gemm_grid), blk, 0, stream>>>(
        Bf16, wt3, statsB, g2, be2, dis, Hs, N);
    gather_k<64, false, false><<<dim3(NBg * 2), blk, 0, stream>>>(
        Hs, dis, b3, row_ptr, esrc, perm, out, nullptr, nullptr, N);
}

// Round 15
// 424.804 us; speedup vs baseline: 1.0099x; 1.0099x over previous
//
#include <hip/hip_runtime.h>
#include <hip/hip_fp16.h>

// ---------------------------------------------------------------------------
// GCN 3-layer forward:  (GCNConv -> BN) x2 -> GCNConv
// N=100000, E=1600000, IN=H=128, OUT=64
// Round 14: round-13 retry with compile fix — nontemporal stores must use
//           native ext_vector types (not HIP_vector_type classes).
// ---------------------------------------------------------------------------

constexpr int BSH = 7;            // 128 nodes per bucket
constexpr int NXCD = 8;

typedef _Float16 half8 __attribute__((ext_vector_type(8)));
typedef float f32x4 __attribute__((ext_vector_type(4)));
typedef unsigned int uint32x4 __attribute__((ext_vector_type(4)));

static __device__ inline ushort f2h(float f) {
    union { __half h; ushort u; } cv;
    cv.h = __float2half_rn(f);
    return cv.u;
}
static __device__ inline float2 h2f2(unsigned int u) {
    union { unsigned int u; __half2 h; } cv;
    cv.u = u;
    return __half22float2(cv.h);
}
static __device__ inline __half2 u2h2(unsigned int u) {
    union { unsigned int u; __half2 h; } cv;
    cv.u = u;
    return cv.h;
}

// packed-f16 accumulate: one uint4 (8 f16) into 4 half2 accumulators
#define ACCPK(v) do { \
    acch[0] = __hadd2(acch[0], u2h2((v).x)); \
    acch[1] = __hadd2(acch[1], u2h2((v).y)); \
    acch[2] = __hadd2(acch[2], u2h2((v).z)); \
    acch[3] = __hadd2(acch[3], u2h2((v).w)); \
} while (0)

// ---- phase A: per-xcd bucket histogram + W^T f16 prep (blocks 0-2) --------
__global__ __launch_bounds__(256) void countwt_k(const int* __restrict__ dst,
                                                 int* __restrict__ hist,
                                                 int E, int EPB, int nbuk,
                                                 const float* __restrict__ W1,
                                                 const float* __restrict__ W2,
                                                 const float* __restrict__ W3,
                                                 ushort* __restrict__ wt1,
                                                 ushort* __restrict__ wt2,
                                                 ushort* __restrict__ wt3) {
    if (blockIdx.x < 3) {
        const float* W; ushort* WT; int OUTD;
        if (blockIdx.x == 0)      { W = W1; WT = wt1; OUTD = 128; }
        else if (blockIdx.x == 1) { W = W2; WT = wt2; OUTD = 128; }
        else                      { W = W3; WT = wt3; OUTD = 64; }
        const int tot = 128 * OUTD;
        for (int idx = threadIdx.x; idx < tot; idx += 256) {
            int nq = idx >> 7;          // output col
            int k  = idx & 127;         // input k
            WT[idx] = f2h(W[k * OUTD + nq]);
        }
        return;
    }
    const int bid = blockIdx.x - 3;
    __shared__ int lh[1024];
    for (int i = threadIdx.x; i < nbuk; i += 256) lh[i] = 0;
    __syncthreads();
    const int e0 = bid * EPB;
    const int e1 = min(e0 + EPB, E);
    for (int e = e0 + threadIdx.x; e < e1; e += 256)
        atomicAdd(&lh[dst[e] >> BSH], 1);
    __syncthreads();
    const int xcd = bid & (NXCD - 1);
    for (int i = threadIdx.x; i < nbuk; i += 256) {
        int v = lh[i];
        if (v) atomicAdd(&hist[xcd * nbuk + i], v);
    }
}

// ---- phase B: scan hist; zero BOTH BN stats banks (stats[0..511]) ---------
__global__ __launch_bounds__(256) void scan_hist_k(const int* __restrict__ hist,
                                                   int* __restrict__ cur,
                                                   int* __restrict__ bstart,
                                                   int* __restrict__ row_ptr,
                                                   float* __restrict__ stats,
                                                   int nbuk, int n, int E) {
    stats[threadIdx.x] = 0.f;
    stats[threadIdx.x + 256] = 0.f;
    const int NT = nbuk * NXCD;          // <= 8192 assumed
    const int C = (NT + 255) / 256;      // <= 32
    int vals[32];
    const int tid = threadIdx.x;
    int sum = 0;
#pragma unroll
    for (int k = 0; k < 32; ++k) {
        if (k >= C) break;
        int key = tid * C + k;
        int v = 0;
        if (key < NT) {
            int b = key >> 3, x = key & 7;
            v = hist[x * nbuk + b];
        }
        vals[k] = v;
        sum += v;
    }
    __shared__ int part[256];
    part[tid] = sum;
    __syncthreads();
    for (int off = 1; off < 256; off <<= 1) {
        int t = 0;
        if (tid >= off) t = part[tid - off];
        __syncthreads();
        part[tid] += t;
        __syncthreads();
    }
    int run = (tid == 0) ? 0 : part[tid - 1];
#pragma unroll
    for (int k = 0; k < 32; ++k) {
        if (k >= C) break;
        int key = tid * C + k;
        if (key < NT) {
            int b = key >> 3, x = key & 7;
            cur[x * nbuk + b] = run;
            if (x == 0) bstart[b] = run;
        }
        run += vals[k];
    }
    if (tid == 0) { bstart[nbuk] = E; row_ptr[n] = E; }
}

// ---- phase C: two-pass LDS-aggregated scatter into (bucket, xcd) segments -
__global__ __launch_bounds__(256) void scatter_bucket_k(const int* __restrict__ src,
                                                        const int* __restrict__ dst,
                                                        int* __restrict__ cur,
                                                        unsigned int* __restrict__ ebuf,
                                                        int E, int EPB, int nbuk) {
    __shared__ int lh[1024];
    __shared__ int base[1024];
    for (int i = threadIdx.x; i < nbuk; i += 256) lh[i] = 0;
    __syncthreads();
    const int e0 = blockIdx.x * EPB;
    const int e1 = min(e0 + EPB, E);
    const int xcd = blockIdx.x & (NXCD - 1);
    for (int e = e0 + threadIdx.x; e < e1; e += 256)
        atomicAdd(&lh[dst[e] >> BSH], 1);
    __syncthreads();
    for (int i = threadIdx.x; i < nbuk; i += 256) {
        int v = lh[i];
        base[i] = v ? atomicAdd(&cur[xcd * nbuk + i], v) : 0;
        lh[i] = 0;                      // becomes cursor
    }
    __syncthreads();
    for (int e = e0 + threadIdx.x; e < e1; e += 256) {
        int d = dst[e];
        int s = src[e];
        int b = d >> BSH;
        int pos = base[b] + atomicAdd(&lh[b], 1);
        ebuf[pos] = ((unsigned int)s << BSH) | (unsigned int)(d & 127);
    }
}

// ---- phase D: per-bucket counting sort -> esrc + row_ptr + dis ------------
__global__ __launch_bounds__(256) void bucket_sort_k(const unsigned int* __restrict__ ebuf,
                                                     const int* __restrict__ bstart,
                                                     int* __restrict__ row_ptr,
                                                     int* __restrict__ esrc,
                                                     float* __restrict__ dis, int n) {
    const int b = blockIdx.x;
    const int beg = bstart[b];
    const int end = bstart[b + 1];
    __shared__ int cnt[128], off[128];
    if (threadIdx.x < 128) cnt[threadIdx.x] = 0;
    __syncthreads();
    for (int i = beg + threadIdx.x; i < end; i += 256)
        atomicAdd(&cnt[ebuf[i] & 127], 1);
    __syncthreads();
    if (threadIdx.x < 128) off[threadIdx.x] = cnt[threadIdx.x];
    __syncthreads();
    for (int d = 1; d < 128; d <<= 1) {
        int t = 0;
        if (threadIdx.x < 128 && threadIdx.x >= d) t = off[threadIdx.x - d];
        __syncthreads();
        if (threadIdx.x < 128) off[threadIdx.x] += t;
        __syncthreads();
    }
    if (threadIdx.x < 128) {
        int deg = cnt[threadIdx.x];
        int ex = off[threadIdx.x] - deg;                // exclusive
        int node = (b << BSH) + threadIdx.x;
        if (node < n) {
            row_ptr[node] = beg + ex;
            dis[node] = rsqrtf((float)deg + 1.0f);      // +1 self loop
        }
        cnt[threadIdx.x] = ex;                          // reuse as cursor
    }
    __syncthreads();
    for (int i = beg + threadIdx.x; i < end; i += 256) {
        unsigned int p = ebuf[i];
        int l = (int)(p & 127);
        int pos = beg + atomicAdd(&cnt[l], 1);
        esrc[pos] = (int)(p >> BSH);
    }
}

// ------- register MFMA GEMM: Hs = f16( (BN(X) @ W) * dis ) -----------------
// Zero-LDS main path. Block = 4 waves x 16 rows = 64 rows. A from global X
// (f32 or f16); B from f16 W^T (L1-resident). When BNIN, each block computes
// BN scale/shift from the raw stats bank (sums|sumsq) + (g,be) into LDS.
// Hs layout: [NCHUNK][N][32 f16], chunk c holds columns [32c, 32c+32).
template <int OUTD, bool XF16, bool BNIN>
__global__ __launch_bounds__(256) void gemm_reg_k(const void* __restrict__ Xv,
                                                  const ushort* __restrict__ WT,
                                                  const float* __restrict__ sums,
                                                  const float* __restrict__ gg,
                                                  const float* __restrict__ be,
                                                  const float* __restrict__ dis,
                                                  ushort* __restrict__ Hs, int nn) {
    constexpr int NCT = OUTD / 16;       // col tiles: 8 or 4
    __shared__ __align__(16) float s_scale[BNIN ? 128 : 4];
    __shared__ __align__(16) float s_shift[BNIN ? 128 : 4];
    if (BNIN) {
        if (threadIdx.x < 128) {
            int c = threadIdx.x;
            float inv_n = 1.0f / (float)nn;
            float m = sums[c] * inv_n;
            float v = sums[c + 128] * inv_n - m * m;
            float sc = rsqrtf(v + 1e-5f) * gg[c];
            s_scale[c] = sc;
            s_shift[c] = be[c] - m * sc;
        }
        __syncthreads();
    }

    const int wave = threadIdx.x >> 6;
    const int lane = threadIdx.x & 63;
    const int l15 = lane & 15;
    const int kg = lane >> 4;            // 0..3
    const int row = blockIdx.x * 64 + wave * 16 + l15;

    // A fragments: row fixed, k = kk*32 + kg*8 + [0..8)
    half8 a[4];
#pragma unroll
    for (int kk = 0; kk < 4; ++kk) {
        float v[8];
        if (row < nn) {
            if (XF16) {
                const uint4* xp = (const uint4*)((const ushort*)Xv + (size_t)row * 128
                                                 + kk * 32 + kg * 8);
                uint4 raw = *xp;
                float2 f;
                f = h2f2(raw.x); v[0] = f.x; v[1] = f.y;
                f = h2f2(raw.y); v[2] = f.x; v[3] = f.y;
                f = h2f2(raw.z); v[4] = f.x; v[5] = f.y;
                f = h2f2(raw.w); v[6] = f.x; v[7] = f.y;
            } else {
                const float4* xp = (const float4*)((const float*)Xv + (size_t)row * 128
                                                   + kk * 32 + kg * 8);
                float4 v0 = xp[0];
                float4 v1 = xp[1];
                v[0] = v0.x; v[1] = v0.y; v[2] = v0.z; v[3] = v0.w;
                v[4] = v1.x; v[5] = v1.y; v[6] = v1.z; v[7] = v1.w;
            }
            if (BNIN) {
                int kq = kk * 8 + kg * 2;
                float4 s0 = ((const float4*)s_scale)[kq];
                float4 s1 = ((const float4*)s_scale)[kq + 1];
                float4 h0 = ((const float4*)s_shift)[kq];
                float4 h1 = ((const float4*)s_shift)[kq + 1];
                v[0] = v[0] * s0.x + h0.x;
                v[1] = v[1] * s0.y + h0.y;
                v[2] = v[2] * s0.z + h0.z;
                v[3] = v[3] * s0.w + h0.w;
                v[4] = v[4] * s1.x + h1.x;
                v[5] = v[5] * s1.y + h1.y;
                v[6] = v[6] * s1.z + h1.z;
                v[7] = v[7] * s1.w + h1.w;
            }
#pragma unroll
            for (int j = 0; j < 8; ++j) a[kk][j] = (_Float16)v[j];
        } else {
#pragma unroll
            for (int j = 0; j < 8; ++j) a[kk][j] = (_Float16)0.f;
        }
    }

    f32x4 acc[NCT];
#pragma unroll
    for (int ct = 0; ct < NCT; ++ct) acc[ct] = (f32x4){0.f, 0.f, 0.f, 0.f};

#pragma unroll
    for (int kk = 0; kk < 4; ++kk) {
#pragma unroll
        for (int ct = 0; ct < NCT; ++ct) {
            half8 bfr = *(const half8*)&WT[(ct * 16 + l15) * 128 + kk * 32 + kg * 8];
            acc[ct] = __builtin_amdgcn_mfma_f32_16x16x32_f16(a[kk], bfr, acc[ct], 0, 0, 0);
        }
    }

    // D: col = lane&15 (within ct), row = kg*4 + reg (within wave tile)
    const int mbase = blockIdx.x * 64 + wave * 16 + kg * 4;
    float dm[4];
#pragma unroll
    for (int reg = 0; reg < 4; ++reg) {
        int m = mbase + reg;
        dm[reg] = (m < nn) ? dis[m] : 0.f;
    }
#pragma unroll
    for (int ct = 0; ct < NCT; ++ct) {
        int ncol = ct * 16 + l15;
        size_t cb = (size_t)(ncol >> 5) * nn * 32 + (ncol & 31);
#pragma unroll
        for (int reg = 0; reg < 4; ++reg) {
            int m = mbase + reg;
            if (m < nn) Hs[cb + (size_t)m * 32] = f2h(acc[ct][reg] * dm[reg]);
        }
    }
}

// ---------------- chunked gather aggregation (+ fused BN stats) ------------
// Per chunk c (32 cols): O[i][32c..32c+32) = dis[i]*(Hs_c[i] + sum Hs_c[src]) + b
// 4 lanes per 64B row; unroll-8; packed-f16 accumulation; non-temporal
// esrc loads + output stores (keep Hs chunk hot in L2).
template <int OUTD, bool STATS, bool OUTF16>
__global__ __launch_bounds__(256) void gather_k(const ushort* __restrict__ Hs,
                                                const float* __restrict__ dis,
                                                const float* __restrict__ b,
                                                const int* __restrict__ row_ptr,
                                                const int* __restrict__ esrc,
                                                void* __restrict__ Ov,
                                                float* __restrict__ sums,
                                                float* __restrict__ sumsq, int n) {
    constexpr int NCHUNK = OUTD / 32;   // 4 or 2

    __shared__ float s_sum[32];
    __shared__ float s_sq[32];
    if (STATS) {
        if (threadIdx.x < 32) { s_sum[threadIdx.x] = 0.f; s_sq[threadIdx.x] = 0.f; }
        __syncthreads();
    }

    const int chunk = blockIdx.x & (NCHUNK - 1);
    const int nblk  = blockIdx.x / NCHUNK;
    const int g     = threadIdx.x >> 2;     // node within block: 0..63
    const int lane  = threadIdx.x & 3;      // uint4 within the 64B row
    const int node  = nblk * 64 + g;

    __half2 acch[4];
#pragma unroll
    for (int c = 0; c < 4; ++c) acch[c] = __half2(__float2half_rn(0.f), __float2half_rn(0.f));
    float o[8];
#pragma unroll
    for (int c = 0; c < 8; ++c) o[c] = 0.f;

    if (node < n) {
        const uint4* Hc = (const uint4*)Hs + (size_t)chunk * n * 4;  // 4 uint4/node

        {   // self row (dis pre-folded into Hs)
            uint4 v = Hc[(size_t)node * 4 + lane];
            ACCPK(v);
        }
        const int beg = row_ptr[node];
        const int end = row_ptr[node + 1];
        int j = beg;
        const int end8 = beg + ((end - beg) & ~7);
        for (; j < end8; j += 8) {
            int s[8];
#pragma unroll
            for (int u = 0; u < 8; ++u) s[u] = __builtin_nontemporal_load(&esrc[j + u]);
            uint4 va[8];
#pragma unroll
            for (int u = 0; u < 8; ++u) va[u] = Hc[(size_t)s[u] * 4 + lane];
#pragma unroll
            for (int u = 0; u < 8; ++u) { ACCPK(va[u]); }
        }
        for (; j < end; ++j) {
            int s = __builtin_nontemporal_load(&esrc[j]);
            uint4 a = Hc[(size_t)s * 4 + lane];
            ACCPK(a);
        }

        float dd = dis[node];
        const float4* B4 = (const float4*)b + chunk * 8 + lane * 2;
        float4 b0 = B4[0];
        float4 b1 = B4[1];
        float2 f0 = __half22float2(acch[0]);
        float2 f1 = __half22float2(acch[1]);
        float2 f2 = __half22float2(acch[2]);
        float2 f3 = __half22float2(acch[3]);
        o[0] = f0.x * dd + b0.x;
        o[1] = f0.y * dd + b0.y;
        o[2] = f1.x * dd + b0.z;
        o[3] = f1.y * dd + b0.w;
        o[4] = f2.x * dd + b1.x;
        o[5] = f2.y * dd + b1.y;
        o[6] = f3.x * dd + b1.z;
        o[7] = f3.y * dd + b1.w;

        if (OUTF16) {
            union { ushort us[8]; uint32x4 v; } pk;
#pragma unroll
            for (int c = 0; c < 8; ++c) pk.us[c] = f2h(o[c]);
            uint32x4* dst4 = (uint32x4*)Ov + (size_t)node * (OUTD / 32) + chunk;
            // one 16B row segment per lane: index by lane within the row
            dst4 = (uint32x4*)Ov + (size_t)node * (OUTD / 8) / 4 * 4;  // unused; recomputed below
            uint32x4* base4 = (uint32x4*)Ov;
            __builtin_nontemporal_store(pk.v,
                &base4[(size_t)node * (OUTD / 8) + chunk * 4 + lane]);
        } else {
            f32x4* O4 = (f32x4*)Ov + (size_t)node * (OUTD / 4) + chunk * 8 + lane * 2;
            f32x4 w0 = {o[0], o[1], o[2], o[3]};
            f32x4 w1 = {o[4], o[5], o[6], o[7]};
            __builtin_nontemporal_store(w0, &O4[0]);
            __builtin_nontemporal_store(w1, &O4[1]);
        }
    }

    if (STATS) {
        // 16 lanes of a wave with equal (lane&3) hold the same 8 columns
        float sv[8], qv[8];
#pragma unroll
        for (int c = 0; c < 8; ++c) { sv[c] = o[c]; qv[c] = o[c] * o[c]; }
#pragma unroll
        for (int c = 0; c < 8; ++c) {
#pragma unroll
            for (int m = 4; m <= 32; m <<= 1) {
                sv[c] += __shfl_xor(sv[c], m);
                qv[c] += __shfl_xor(qv[c], m);
            }
        }
        if ((threadIdx.x & 63) < 4) {
            int c0 = lane * 8;
#pragma unroll
            for (int c = 0; c < 8; ++c) {
                atomicAdd(&s_sum[c0 + c], sv[c]);
                atomicAdd(&s_sq[c0 + c], qv[c]);
            }
        }
        __syncthreads();
        if (threadIdx.x < 32) {
            atomicAdd(&sums[chunk * 32 + threadIdx.x], s_sum[threadIdx.x]);
            atomicAdd(&sumsq[chunk * 32 + threadIdx.x], s_sq[threadIdx.x]);
        }
    }
}

// ---------------------------------------------------------------------------
extern "C" void kernel_launch(void* const* d_in, const int* in_sizes, int n_in,
                              void* d_out, int out_size, void* d_ws, size_t ws_size,
                              hipStream_t stream) {
    const float* x   = (const float*)d_in[0];
    const int*   ei  = (const int*)d_in[1];
    const float* W1  = (const float*)d_in[2];
    const float* b1  = (const float*)d_in[3];
    const float* g1  = (const float*)d_in[4];
    const float* be1 = (const float*)d_in[5];
    const float* W2  = (const float*)d_in[6];
    const float* b2  = (const float*)d_in[7];
    const float* g2  = (const float*)d_in[8];
    const float* be2 = (const float*)d_in[9];
    const float* W3  = (const float*)d_in[10];
    const float* b3  = (const float*)d_in[11];
    float* out = (float*)d_out;

    const int N = in_sizes[0] / 128;
    const int E = in_sizes[1] / 2;
    const int* src = ei;
    const int* dst = ei + E;
    const int NBUK = (N + 127) >> BSH;

    // ---- workspace layout ----
    float* wsp   = (float*)d_ws;
    float* dis   = wsp;                               // N f32
    float* stats = wsp + N;                           // 512 f32 (2 banks)
    ushort* wt1  = (ushort*)(stats + 512);            // 128*128 f16
    ushort* wt2  = wt1 + 128 * 128;
    ushort* wt3  = wt2 + 128 * 128;                   // 128*64 f16
    int*   hist   = (int*)(wt3 + 128 * 64);           // NBUK*8
    int*   cur    = hist + NBUK * NXCD;               // NBUK*8
    int*   bstart = cur + NBUK * NXCD;                // NBUK+1
    int*   row_ptr = bstart + NBUK + 1 + 63;          // N+1
    float* bufA  = (float*)((((uintptr_t)(row_ptr + N + 1)) + 255) & ~(uintptr_t)255);
    float* bufB  = bufA + (size_t)N * 128;            // N*128 region (f16 used)
    unsigned int* ebuf = (unsigned int*)(bufB + (size_t)N * 128);  // E u32
    int*   esrc  = (int*)(ebuf + E);                  // E int

    ushort* Hs  = (ushort*)bufA;                      // [NCHUNK][N][32] f16
    ushort* Bf16 = (ushort*)bufB;                     // [N][128] f16 inter-layer

    float* statsA = stats;        // sums|sumsq layer 1
    float* statsB = stats + 256;  // sums|sumsq layer 2

    const int BS = 256;
    dim3 blk(BS);
    const int SGRID = 128;                 // count/scatter blocks (multiple of 8)
    const int EPB = (E + SGRID - 1) / SGRID;

    // ---- bucket-sorted CSR build ----
    hipMemsetAsync(hist, 0, (size_t)NBUK * NXCD * 4, stream);
    countwt_k<<<dim3(SGRID + 3), blk, 0, stream>>>(dst, hist, E, EPB, NBUK,
                                                   W1, W2, W3, wt1, wt2, wt3);
    scan_hist_k<<<dim3(1), blk, 0, stream>>>(hist, cur, bstart, row_ptr, stats, NBUK, N, E);
    scatter_bucket_k<<<dim3(SGRID), blk, 0, stream>>>(src, dst, cur, ebuf, E, EPB, NBUK);
    bucket_sort_k<<<dim3(NBUK), blk, 0, stream>>>(ebuf, bstart, row_ptr, esrc, dis, N);

    const int gemm_grid = (N + 63) / 64;
    const int NBg = (N + 63) / 64;      // gather node-blocks (64 nodes/block)

    // ---- layer 1 ----
    gemm_reg_k<128, false, false><<<dim3(gemm_grid), blk, 0, stream>>>(
        x, wt1, nullptr, nullptr, nullptr, dis, Hs, N);
    gather_k<128, true, true><<<dim3(NBg * 4), blk, 0, stream>>>(
        Hs, dis, b1, row_ptr, esrc, Bf16, statsA, statsA + 128, N);

    // ---- layer 2 (BN computed per-block from statsA inside GEMM) ----
    gemm_reg_k<128, true, true><<<dim3(gemm_grid), blk, 0, stream>>>(
        Bf16, wt2, statsA, g1, be1, dis, Hs, N);
    gather_k<128, true, true><<<dim3(NBg * 4), blk, 0, stream>>>(
        Hs, dis, b2, row_ptr, esrc, Bf16, statsB, statsB + 128, N);

    // ---- layer 3 (OUT = 64, BN from statsB, f32 straight to d_out) ----
    gemm_reg_k<64, true, true><<<dim3(gemm_grid), blk, 0, stream>>>(
        Bf16, wt3, statsB, g2, be2, dis, Hs, N);
    gather_k<64, false, false><<<dim3(NBg * 2), blk, 0, stream>>>(
        Hs, dis, b3, row_ptr, esrc, out, nullptr, nullptr, N);
}

// Round 16
// 404.295 us; speedup vs baseline: 1.0611x; 1.0507x over previous
//
#include <hip/hip_runtime.h>
#include <hip/hip_fp16.h>

// ---------------------------------------------------------------------------
// GCN 3-layer forward:  (GCNConv -> BN) x2 -> GCNConv
// N=100000, E=1600000, IN=H=128, OUT=64
// Round 15: revert to round-11 config (best measured, 405 us) — nt-hints
//           (r14) and degree-sort (r12) both regressed and are removed.
//           Gather: 4 lanes/64B row, unroll-8, packed-f16 accumulation.
//           GEMM: zero-LDS register MFMA, BN fused. Build: bucket CSR.
// ---------------------------------------------------------------------------

constexpr int BSH = 7;            // 128 nodes per bucket
constexpr int NXCD = 8;

typedef _Float16 half8 __attribute__((ext_vector_type(8)));
typedef float f32x4 __attribute__((ext_vector_type(4)));

static __device__ inline ushort f2h(float f) {
    union { __half h; ushort u; } cv;
    cv.h = __float2half_rn(f);
    return cv.u;
}
static __device__ inline float2 h2f2(unsigned int u) {
    union { unsigned int u; __half2 h; } cv;
    cv.u = u;
    return __half22float2(cv.h);
}
static __device__ inline __half2 u2h2(unsigned int u) {
    union { unsigned int u; __half2 h; } cv;
    cv.u = u;
    return cv.h;
}

// packed-f16 accumulate: one uint4 (8 f16) into 4 half2 accumulators
#define ACCPK(v) do { \
    acch[0] = __hadd2(acch[0], u2h2((v).x)); \
    acch[1] = __hadd2(acch[1], u2h2((v).y)); \
    acch[2] = __hadd2(acch[2], u2h2((v).z)); \
    acch[3] = __hadd2(acch[3], u2h2((v).w)); \
} while (0)

// ---- phase A: per-xcd bucket histogram + W^T f16 prep (blocks 0-2) --------
__global__ __launch_bounds__(256) void countwt_k(const int* __restrict__ dst,
                                                 int* __restrict__ hist,
                                                 int E, int EPB, int nbuk,
                                                 const float* __restrict__ W1,
                                                 const float* __restrict__ W2,
                                                 const float* __restrict__ W3,
                                                 ushort* __restrict__ wt1,
                                                 ushort* __restrict__ wt2,
                                                 ushort* __restrict__ wt3) {
    if (blockIdx.x < 3) {
        const float* W; ushort* WT; int OUTD;
        if (blockIdx.x == 0)      { W = W1; WT = wt1; OUTD = 128; }
        else if (blockIdx.x == 1) { W = W2; WT = wt2; OUTD = 128; }
        else                      { W = W3; WT = wt3; OUTD = 64; }
        const int tot = 128 * OUTD;
        for (int idx = threadIdx.x; idx < tot; idx += 256) {
            int nq = idx >> 7;          // output col
            int k  = idx & 127;         // input k
            WT[idx] = f2h(W[k * OUTD + nq]);
        }
        return;
    }
    const int bid = blockIdx.x - 3;
    __shared__ int lh[1024];
    for (int i = threadIdx.x; i < nbuk; i += 256) lh[i] = 0;
    __syncthreads();
    const int e0 = bid * EPB;
    const int e1 = min(e0 + EPB, E);
    for (int e = e0 + threadIdx.x; e < e1; e += 256)
        atomicAdd(&lh[dst[e] >> BSH], 1);
    __syncthreads();
    const int xcd = bid & (NXCD - 1);
    for (int i = threadIdx.x; i < nbuk; i += 256) {
        int v = lh[i];
        if (v) atomicAdd(&hist[xcd * nbuk + i], v);
    }
}

// ---- phase B: scan hist; zero BOTH BN stats banks (stats[0..511]) ---------
__global__ __launch_bounds__(256) void scan_hist_k(const int* __restrict__ hist,
                                                   int* __restrict__ cur,
                                                   int* __restrict__ bstart,
                                                   int* __restrict__ row_ptr,
                                                   float* __restrict__ stats,
                                                   int nbuk, int n, int E) {
    stats[threadIdx.x] = 0.f;
    stats[threadIdx.x + 256] = 0.f;
    const int NT = nbuk * NXCD;          // <= 8192 assumed
    const int C = (NT + 255) / 256;      // <= 32
    int vals[32];
    const int tid = threadIdx.x;
    int sum = 0;
#pragma unroll
    for (int k = 0; k < 32; ++k) {
        if (k >= C) break;
        int key = tid * C + k;
        int v = 0;
        if (key < NT) {
            int b = key >> 3, x = key & 7;
            v = hist[x * nbuk + b];
        }
        vals[k] = v;
        sum += v;
    }
    __shared__ int part[256];
    part[tid] = sum;
    __syncthreads();
    for (int off = 1; off < 256; off <<= 1) {
        int t = 0;
        if (tid >= off) t = part[tid - off];
        __syncthreads();
        part[tid] += t;
        __syncthreads();
    }
    int run = (tid == 0) ? 0 : part[tid - 1];
#pragma unroll
    for (int k = 0; k < 32; ++k) {
        if (k >= C) break;
        int key = tid * C + k;
        if (key < NT) {
            int b = key >> 3, x = key & 7;
            cur[x * nbuk + b] = run;
            if (x == 0) bstart[b] = run;
        }
        run += vals[k];
    }
    if (tid == 0) { bstart[nbuk] = E; row_ptr[n] = E; }
}

// ---- phase C: two-pass LDS-aggregated scatter into (bucket, xcd) segments -
__global__ __launch_bounds__(256) void scatter_bucket_k(const int* __restrict__ src,
                                                        const int* __restrict__ dst,
                                                        int* __restrict__ cur,
                                                        unsigned int* __restrict__ ebuf,
                                                        int E, int EPB, int nbuk) {
    __shared__ int lh[1024];
    __shared__ int base[1024];
    for (int i = threadIdx.x; i < nbuk; i += 256) lh[i] = 0;
    __syncthreads();
    const int e0 = blockIdx.x * EPB;
    const int e1 = min(e0 + EPB, E);
    const int xcd = blockIdx.x & (NXCD - 1);
    for (int e = e0 + threadIdx.x; e < e1; e += 256)
        atomicAdd(&lh[dst[e] >> BSH], 1);
    __syncthreads();
    for (int i = threadIdx.x; i < nbuk; i += 256) {
        int v = lh[i];
        base[i] = v ? atomicAdd(&cur[xcd * nbuk + i], v) : 0;
        lh[i] = 0;                      // becomes cursor
    }
    __syncthreads();
    for (int e = e0 + threadIdx.x; e < e1; e += 256) {
        int d = dst[e];
        int s = src[e];
        int b = d >> BSH;
        int pos = base[b] + atomicAdd(&lh[b], 1);
        ebuf[pos] = ((unsigned int)s << BSH) | (unsigned int)(d & 127);
    }
}

// ---- phase D: per-bucket counting sort -> esrc + row_ptr + dis ------------
__global__ __launch_bounds__(256) void bucket_sort_k(const unsigned int* __restrict__ ebuf,
                                                     const int* __restrict__ bstart,
                                                     int* __restrict__ row_ptr,
                                                     int* __restrict__ esrc,
                                                     float* __restrict__ dis, int n) {
    const int b = blockIdx.x;
    const int beg = bstart[b];
    const int end = bstart[b + 1];
    __shared__ int cnt[128], off[128];
    if (threadIdx.x < 128) cnt[threadIdx.x] = 0;
    __syncthreads();
    for (int i = beg + threadIdx.x; i < end; i += 256)
        atomicAdd(&cnt[ebuf[i] & 127], 1);
    __syncthreads();
    if (threadIdx.x < 128) off[threadIdx.x] = cnt[threadIdx.x];
    __syncthreads();
    for (int d = 1; d < 128; d <<= 1) {
        int t = 0;
        if (threadIdx.x < 128 && threadIdx.x >= d) t = off[threadIdx.x - d];
        __syncthreads();
        if (threadIdx.x < 128) off[threadIdx.x] += t;
        __syncthreads();
    }
    if (threadIdx.x < 128) {
        int deg = cnt[threadIdx.x];
        int ex = off[threadIdx.x] - deg;                // exclusive
        int node = (b << BSH) + threadIdx.x;
        if (node < n) {
            row_ptr[node] = beg + ex;
            dis[node] = rsqrtf((float)deg + 1.0f);      // +1 self loop
        }
        cnt[threadIdx.x] = ex;                          // reuse as cursor
    }
    __syncthreads();
    for (int i = beg + threadIdx.x; i < end; i += 256) {
        unsigned int p = ebuf[i];
        int l = (int)(p & 127);
        int pos = beg + atomicAdd(&cnt[l], 1);
        esrc[pos] = (int)(p >> BSH);
    }
}

// ------- register MFMA GEMM: Hs = f16( (BN(X) @ W) * dis ) -----------------
// Zero-LDS main path. Block = 4 waves x 16 rows = 64 rows. A from global X
// (f32 or f16); B from f16 W^T (L1-resident). When BNIN, each block computes
// BN scale/shift from the raw stats bank (sums|sumsq) + (g,be) into LDS.
// Hs layout: [NCHUNK][N][32 f16], chunk c holds columns [32c, 32c+32).
template <int OUTD, bool XF16, bool BNIN>
__global__ __launch_bounds__(256) void gemm_reg_k(const void* __restrict__ Xv,
                                                  const ushort* __restrict__ WT,
                                                  const float* __restrict__ sums,
                                                  const float* __restrict__ gg,
                                                  const float* __restrict__ be,
                                                  const float* __restrict__ dis,
                                                  ushort* __restrict__ Hs, int nn) {
    constexpr int NCT = OUTD / 16;       // col tiles: 8 or 4
    __shared__ __align__(16) float s_scale[BNIN ? 128 : 4];
    __shared__ __align__(16) float s_shift[BNIN ? 128 : 4];
    if (BNIN) {
        if (threadIdx.x < 128) {
            int c = threadIdx.x;
            float inv_n = 1.0f / (float)nn;
            float m = sums[c] * inv_n;
            float v = sums[c + 128] * inv_n - m * m;
            float sc = rsqrtf(v + 1e-5f) * gg[c];
            s_scale[c] = sc;
            s_shift[c] = be[c] - m * sc;
        }
        __syncthreads();
    }

    const int wave = threadIdx.x >> 6;
    const int lane = threadIdx.x & 63;
    const int l15 = lane & 15;
    const int kg = lane >> 4;            // 0..3
    const int row = blockIdx.x * 64 + wave * 16 + l15;

    // A fragments: row fixed, k = kk*32 + kg*8 + [0..8)
    half8 a[4];
#pragma unroll
    for (int kk = 0; kk < 4; ++kk) {
        float v[8];
        if (row < nn) {
            if (XF16) {
                const uint4* xp = (const uint4*)((const ushort*)Xv + (size_t)row * 128
                                                 + kk * 32 + kg * 8);
                uint4 raw = *xp;
                float2 f;
                f = h2f2(raw.x); v[0] = f.x; v[1] = f.y;
                f = h2f2(raw.y); v[2] = f.x; v[3] = f.y;
                f = h2f2(raw.z); v[4] = f.x; v[5] = f.y;
                f = h2f2(raw.w); v[6] = f.x; v[7] = f.y;
            } else {
                const float4* xp = (const float4*)((const float*)Xv + (size_t)row * 128
                                                   + kk * 32 + kg * 8);
                float4 v0 = xp[0];
                float4 v1 = xp[1];
                v[0] = v0.x; v[1] = v0.y; v[2] = v0.z; v[3] = v0.w;
                v[4] = v1.x; v[5] = v1.y; v[6] = v1.z; v[7] = v1.w;
            }
            if (BNIN) {
                int kq = kk * 8 + kg * 2;
                float4 s0 = ((const float4*)s_scale)[kq];
                float4 s1 = ((const float4*)s_scale)[kq + 1];
                float4 h0 = ((const float4*)s_shift)[kq];
                float4 h1 = ((const float4*)s_shift)[kq + 1];
                v[0] = v[0] * s0.x + h0.x;
                v[1] = v[1] * s0.y + h0.y;
                v[2] = v[2] * s0.z + h0.z;
                v[3] = v[3] * s0.w + h0.w;
                v[4] = v[4] * s1.x + h1.x;
                v[5] = v[5] * s1.y + h1.y;
                v[6] = v[6] * s1.z + h1.z;
                v[7] = v[7] * s1.w + h1.w;
            }
#pragma unroll
            for (int j = 0; j < 8; ++j) a[kk][j] = (_Float16)v[j];
        } else {
#pragma unroll
            for (int j = 0; j < 8; ++j) a[kk][j] = (_Float16)0.f;
        }
    }

    f32x4 acc[NCT];
#pragma unroll
    for (int ct = 0; ct < NCT; ++ct) acc[ct] = (f32x4){0.f, 0.f, 0.f, 0.f};

#pragma unroll
    for (int kk = 0; kk < 4; ++kk) {
#pragma unroll
        for (int ct = 0; ct < NCT; ++ct) {
            half8 bfr = *(const half8*)&WT[(ct * 16 + l15) * 128 + kk * 32 + kg * 8];
            acc[ct] = __builtin_amdgcn_mfma_f32_16x16x32_f16(a[kk], bfr, acc[ct], 0, 0, 0);
        }
    }

    // D: col = lane&15 (within ct), row = kg*4 + reg (within wave tile)
    const int mbase = blockIdx.x * 64 + wave * 16 + kg * 4;
    float dm[4];
#pragma unroll
    for (int reg = 0; reg < 4; ++reg) {
        int m = mbase + reg;
        dm[reg] = (m < nn) ? dis[m] : 0.f;
    }
#pragma unroll
    for (int ct = 0; ct < NCT; ++ct) {
        int ncol = ct * 16 + l15;
        size_t cb = (size_t)(ncol >> 5) * nn * 32 + (ncol & 31);
#pragma unroll
        for (int reg = 0; reg < 4; ++reg) {
            int m = mbase + reg;
            if (m < nn) Hs[cb + (size_t)m * 32] = f2h(acc[ct][reg] * dm[reg]);
        }
    }
}

// ---------------- chunked gather aggregation (+ fused BN stats) ------------
// Per chunk c (32 cols): O[i][32c..32c+32) = dis[i]*(Hs_c[i] + sum Hs_c[src]) + b
// 4 lanes per 64B row; unroll-8 pipeline; packed-f16 accumulation.
template <int OUTD, bool STATS, bool OUTF16>
__global__ __launch_bounds__(256) void gather_k(const ushort* __restrict__ Hs,
                                                const float* __restrict__ dis,
                                                const float* __restrict__ b,
                                                const int* __restrict__ row_ptr,
                                                const int* __restrict__ esrc,
                                                void* __restrict__ Ov,
                                                float* __restrict__ sums,
                                                float* __restrict__ sumsq, int n) {
    constexpr int NCHUNK = OUTD / 32;   // 4 or 2

    __shared__ float s_sum[32];
    __shared__ float s_sq[32];
    if (STATS) {
        if (threadIdx.x < 32) { s_sum[threadIdx.x] = 0.f; s_sq[threadIdx.x] = 0.f; }
        __syncthreads();
    }

    const int chunk = blockIdx.x & (NCHUNK - 1);
    const int nblk  = blockIdx.x / NCHUNK;
    const int g     = threadIdx.x >> 2;     // node within block: 0..63
    const int lane  = threadIdx.x & 3;      // uint4 within the 64B row
    const int node  = nblk * 64 + g;

    __half2 acch[4];
#pragma unroll
    for (int c = 0; c < 4; ++c) acch[c] = __half2(__float2half_rn(0.f), __float2half_rn(0.f));
    float o[8];
#pragma unroll
    for (int c = 0; c < 8; ++c) o[c] = 0.f;

    if (node < n) {
        const uint4* Hc = (const uint4*)Hs + (size_t)chunk * n * 4;  // 4 uint4/node

        {   // self row (dis pre-folded into Hs)
            uint4 v = Hc[(size_t)node * 4 + lane];
            ACCPK(v);
        }
        const int beg = row_ptr[node];
        const int end = row_ptr[node + 1];
        int j = beg;
        const int end8 = beg + ((end - beg) & ~7);
        for (; j < end8; j += 8) {
            int s[8];
#pragma unroll
            for (int u = 0; u < 8; ++u) s[u] = esrc[j + u];
            uint4 va[8];
#pragma unroll
            for (int u = 0; u < 8; ++u) va[u] = Hc[(size_t)s[u] * 4 + lane];
#pragma unroll
            for (int u = 0; u < 8; ++u) { ACCPK(va[u]); }
        }
        for (; j < end; ++j) {
            int s = esrc[j];
            uint4 a = Hc[(size_t)s * 4 + lane];
            ACCPK(a);
        }

        float dd = dis[node];
        const float4* B4 = (const float4*)b + chunk * 8 + lane * 2;
        float4 b0 = B4[0];
        float4 b1 = B4[1];
        float2 f0 = __half22float2(acch[0]);
        float2 f1 = __half22float2(acch[1]);
        float2 f2 = __half22float2(acch[2]);
        float2 f3 = __half22float2(acch[3]);
        o[0] = f0.x * dd + b0.x;
        o[1] = f0.y * dd + b0.y;
        o[2] = f1.x * dd + b0.z;
        o[3] = f1.y * dd + b0.w;
        o[4] = f2.x * dd + b1.x;
        o[5] = f2.y * dd + b1.y;
        o[6] = f3.x * dd + b1.z;
        o[7] = f3.y * dd + b1.w;

        if (OUTF16) {
            union { ushort us[8]; uint4 v; } pk;
#pragma unroll
            for (int c = 0; c < 8; ++c) pk.us[c] = f2h(o[c]);
            ((uint4*)Ov)[(size_t)node * (OUTD / 8) + chunk * 4 + lane] = pk.v;
        } else {
            float4* O4 = (float4*)Ov + (size_t)node * (OUTD / 4) + chunk * 8 + lane * 2;
            O4[0] = make_float4(o[0], o[1], o[2], o[3]);
            O4[1] = make_float4(o[4], o[5], o[6], o[7]);
        }
    }

    if (STATS) {
        // 16 lanes of a wave with equal (lane&3) hold the same 8 columns
        float sv[8], qv[8];
#pragma unroll
        for (int c = 0; c < 8; ++c) { sv[c] = o[c]; qv[c] = o[c] * o[c]; }
#pragma unroll
        for (int c = 0; c < 8; ++c) {
#pragma unroll
            for (int m = 4; m <= 32; m <<= 1) {
                sv[c] += __shfl_xor(sv[c], m);
                qv[c] += __shfl_xor(qv[c], m);
            }
        }
        if ((threadIdx.x & 63) < 4) {
            int c0 = lane * 8;
#pragma unroll
            for (int c = 0; c < 8; ++c) {
                atomicAdd(&s_sum[c0 + c], sv[c]);
                atomicAdd(&s_sq[c0 + c], qv[c]);
            }
        }
        __syncthreads();
        if (threadIdx.x < 32) {
            atomicAdd(&sums[chunk * 32 + threadIdx.x], s_sum[threadIdx.x]);
            atomicAdd(&sumsq[chunk * 32 + threadIdx.x], s_sq[threadIdx.x]);
        }
    }
}

// ---------------------------------------------------------------------------
extern "C" void kernel_launch(void* const* d_in, const int* in_sizes, int n_in,
                              void* d_out, int out_size, void* d_ws, size_t ws_size,
                              hipStream_t stream) {
    const float* x   = (const float*)d_in[0];
    const int*   ei  = (const int*)d_in[1];
    const float* W1  = (const float*)d_in[2];
    const float* b1  = (const float*)d_in[3];
    const float* g1  = (const float*)d_in[4];
    const float* be1 = (const float*)d_in[5];
    const float* W2  = (const float*)d_in[6];
    const float* b2  = (const float*)d_in[7];
    const float* g2  = (const float*)d_in[8];
    const float* be2 = (const float*)d_in[9];
    const float* W3  = (const float*)d_in[10];
    const float* b3  = (const float*)d_in[11];
    float* out = (float*)d_out;

    const int N = in_sizes[0] / 128;
    const int E = in_sizes[1] / 2;
    const int* src = ei;
    const int* dst = ei + E;
    const int NBUK = (N + 127) >> BSH;

    // ---- workspace layout ----
    float* wsp   = (float*)d_ws;
    float* dis   = wsp;                               // N f32
    float* stats = wsp + N;                           // 512 f32 (2 banks)
    ushort* wt1  = (ushort*)(stats + 512);            // 128*128 f16
    ushort* wt2  = wt1 + 128 * 128;
    ushort* wt3  = wt2 + 128 * 128;                   // 128*64 f16
    int*   hist   = (int*)(wt3 + 128 * 64);           // NBUK*8
    int*   cur    = hist + NBUK * NXCD;               // NBUK*8
    int*   bstart = cur + NBUK * NXCD;                // NBUK+1
    int*   row_ptr = bstart + NBUK + 1 + 63;          // N+1
    float* bufA  = (float*)((((uintptr_t)(row_ptr + N + 1)) + 255) & ~(uintptr_t)255);
    float* bufB  = bufA + (size_t)N * 128;            // N*128 region (f16 used)
    unsigned int* ebuf = (unsigned int*)(bufB + (size_t)N * 128);  // E u32
    int*   esrc  = (int*)(ebuf + E);                  // E int

    ushort* Hs  = (ushort*)bufA;                      // [NCHUNK][N][32] f16
    ushort* Bf16 = (ushort*)bufB;                     // [N][128] f16 inter-layer

    float* statsA = stats;        // sums|sumsq layer 1
    float* statsB = stats + 256;  // sums|sumsq layer 2

    const int BS = 256;
    dim3 blk(BS);
    const int SGRID = 128;                 // count/scatter blocks (multiple of 8)
    const int EPB = (E + SGRID - 1) / SGRID;

    // ---- bucket-sorted CSR build ----
    hipMemsetAsync(hist, 0, (size_t)NBUK * NXCD * 4, stream);
    countwt_k<<<dim3(SGRID + 3), blk, 0, stream>>>(dst, hist, E, EPB, NBUK,
                                                   W1, W2, W3, wt1, wt2, wt3);
    scan_hist_k<<<dim3(1), blk, 0, stream>>>(hist, cur, bstart, row_ptr, stats, NBUK, N, E);
    scatter_bucket_k<<<dim3(SGRID), blk, 0, stream>>>(src, dst, cur, ebuf, E, EPB, NBUK);
    bucket_sort_k<<<dim3(NBUK), blk, 0, stream>>>(ebuf, bstart, row_ptr, esrc, dis, N);

    const int gemm_grid = (N + 63) / 64;
    const int NBg = (N + 63) / 64;      // gather node-blocks (64 nodes/block)

    // ---- layer 1 ----
    gemm_reg_k<128, false, false><<<dim3(gemm_grid), blk, 0, stream>>>(
        x, wt1, nullptr, nullptr, nullptr, dis, Hs, N);
    gather_k<128, true, true><<<dim3(NBg * 4), blk, 0, stream>>>(
        Hs, dis, b1, row_ptr, esrc, Bf16, statsA, statsA + 128, N);

    // ---- layer 2 (BN computed per-block from statsA inside GEMM) ----
    gemm_reg_k<128, true, true><<<dim3(gemm_grid), blk, 0, stream>>>(
        Bf16, wt2, statsA, g1, be1, dis, Hs, N);
    gather_k<128, true, true><<<dim3(NBg * 4), blk, 0, stream>>>(
        Hs, dis, b2, row_ptr, esrc, Bf16, statsB, statsB + 128, N);

    // ---- layer 3 (OUT = 64, BN from statsB, f32 straight to d_out) ----
    gemm_reg_k<64, true, true><<<dim3(gemm_grid), blk, 0, stream>>>(
        Bf16, wt3, statsB, g2, be2, dis, Hs, N);
    gather_k<64, false, false><<<dim3(NBg * 2), blk, 0, stream>>>(
        Hs, dis, b3, row_ptr, esrc, out, nullptr, nullptr, N);
}